// Round 4
// baseline (284.502 us; speedup 1.0000x reference)
//
#include <hip/hip_runtime.h>

typedef __attribute__((ext_vector_type(8))) __bf16 bf16x8;
typedef __attribute__((ext_vector_type(4))) float f32x4;
typedef const __attribute__((address_space(1))) unsigned int gas_u32;
typedef __attribute__((address_space(3))) unsigned int las_u32;

__device__ __forceinline__ unsigned short f2bf(float f) {
  unsigned u = __builtin_bit_cast(unsigned, f);
  u = (u + 0x7FFFu + ((u >> 16) & 1u)) >> 16;
  return (unsigned short)u;
}
__device__ __forceinline__ float bf2f(unsigned short h) {
  return __builtin_bit_cast(float, (unsigned)h << 16);
}

// ---------------- sum of squares (for g/||w||) ----------------
__global__ __launch_bounds__(256) void k_sumsq(const float* __restrict__ w, int n4,
                                               float* __restrict__ out) {
  int tid = threadIdx.x;
  float s = 0.f;
  for (int i = blockIdx.x * 256 + tid; i < n4; i += gridDim.x * 256) {
    float4 v = ((const float4*)w)[i];
    s += v.x * v.x + v.y * v.y + v.z * v.z + v.w * v.w;
  }
  for (int off = 32; off; off >>= 1) s += __shfl_down(s, off);
  __shared__ float red[4];
  if ((tid & 63) == 0) red[tid >> 6] = s;
  __syncthreads();
  if (tid == 0) atomicAdd(out, red[0] + red[1] + red[2] + red[3]);
}

// ---------------- f32 -> bf16 convert ----------------
__global__ __launch_bounds__(256) void k_cvt(const float* __restrict__ in,
                                             unsigned short* __restrict__ out, int n8) {
  for (int i = blockIdx.x * 256 + threadIdx.x; i < n8; i += gridDim.x * 256) {
    float4 a = ((const float4*)in)[2 * i];
    float4 b = ((const float4*)in)[2 * i + 1];
    uint4 o;
    o.x = f2bf(a.x) | ((unsigned)f2bf(a.y) << 16);
    o.y = f2bf(a.z) | ((unsigned)f2bf(a.w) << 16);
    o.z = f2bf(b.x) | ((unsigned)f2bf(b.y) << 16);
    o.w = f2bf(b.z) | ((unsigned)f2bf(b.w) << 16);
    ((uint4*)out)[i] = o;
  }
}

// ======== GEMM1: 256x256 8-phase schedule (m201 port): C = relu(s*(A@B^T)+bias) ========
// A [M][K], B [N][K] bf16 row-major. BK=64, 512 thr = 8 waves (2M x 4N), wave out
// 128x64 (acc[8][4]). LDS 128 KiB: lA[2buf][2 mq-units][128*64], lB[2buf][2 nq-units].
// Unit = consumption-aligned gather subtile (16KB, 2 loads/thread):
//   A(mq) = global rows {wm*128 + mq*64 + r} for wm=0,1; B(nq) = {wn*64 + nq*32 + r}.
// Phase k of tile t: {ds_reads for THIS phase's MFMA; stage 1 unit; barrier;
//   lgkmcnt(0); setprio1; 16 MFMA; setprio0; barrier}. vmcnt(6) only at phase 4.
// Stage pattern: PH1: A1(t+1)->nb; PH2: A0(t+2)->cb; PH3: B0(t+2)->cb; PH4: B1(t+2)->cb.
// Steady state: after PH4(t)'s vmcnt(6), ALL tile-(t+1) units landed, 3 units (t+2)
// in flight. WAR: every stage targets a region last read >=2 barriers earlier.
// Tail: stage source clamps to tile nt-1 (idempotent byte-identical rewrite).
__global__ __launch_bounds__(512, 2) void k_gemm8p(
    const unsigned short* __restrict__ A, const unsigned short* __restrict__ B,
    const float* __restrict__ bias, const float* __restrict__ gptr,
    const float* __restrict__ ssptr, unsigned short* __restrict__ C,
    int M, int N, int K, int nbn) {
  __shared__ __align__(16) unsigned short lA[2 * 2 * 8192];
  __shared__ __align__(16) unsigned short lB[2 * 2 * 8192];
  const int tid = threadIdx.x;
  const int wid = tid >> 6, lane = tid & 63;
  const int l15 = lane & 15, l4 = lane >> 4;
  const int wm = wid >> 2, wn = wid & 3;

  // bijective XCD swizzle (gridDim.x % 8 == 0)
  int nwg = gridDim.x;
  int wg = (blockIdx.x & 7) * (nwg >> 3) + (blockIdx.x >> 3);
  int bm = wg / nbn, bn = wg % nbn;

  const unsigned short* Ab = A + (size_t)bm * 256 * K;
  const unsigned short* Bb = B + (size_t)bn * 256 * K;
  const int nt = K >> 6;

  // staging precompute (j = 0,1): phys row in unit, swizzled source col, global row base
  int ldsoff[2], scolj[2], rowAj[2], rowBj[2];
#pragma unroll
  for (int j = 0; j < 2; ++j) {
    int eoff = (j * 8 + wid) * 512 + lane * 8;
    int pr = eoff >> 6;
    int chunk = (eoff >> 3) & 7;
    ldsoff[j] = eoff;
    scolj[j] = (chunk ^ (pr & 7)) << 3;
    rowAj[j] = (pr >> 6) * 128 + (pr & 63);  // + mq*64
    rowBj[j] = (pr >> 5) * 64 + (pr & 31);   // + nq*32
  }

#define STAGE_A(MQ, TS, BUFI)                                                     \
  {                                                                               \
    int ts_ = (TS) < nt ? (TS) : nt - 1;                                          \
    _Pragma("unroll") for (int j = 0; j < 2; ++j) {                               \
      __builtin_amdgcn_global_load_lds(                                           \
          (gas_u32*)(Ab + (size_t)(rowAj[j] + (MQ)*64) * K + ts_ * 64 + scolj[j]),\
          (las_u32*)(lA + (BUFI)*16384 + (MQ)*8192 + ldsoff[j]), 16, 0, 0);       \
    }                                                                             \
  }

#define STAGE_B(NQ, TS, BUFI)                                                     \
  {                                                                               \
    int ts_ = (TS) < nt ? (TS) : nt - 1;                                          \
    _Pragma("unroll") for (int j = 0; j < 2; ++j) {                               \
      __builtin_amdgcn_global_load_lds(                                           \
          (gas_u32*)(Bb + (size_t)(rowBj[j] + (NQ)*32) * K + ts_ * 64 + scolj[j]),\
          (las_u32*)(lB + (BUFI)*16384 + (NQ)*8192 + ldsoff[j]), 16, 0, 0);       \
    }                                                                             \
  }

#define LDA(DST, MQ, BUFE)                                                        \
  _Pragma("unroll") for (int mi = 0; mi < 4; ++mi) {                              \
    int pr = wm * 64 + mi * 16 + l15;                                             \
    const unsigned short* ap = lA + (BUFE) + (MQ)*8192 + pr * 64;                 \
    int s8 = pr & 7;                                                              \
    DST[mi][0] = *(const bf16x8*)(ap + ((l4 ^ s8) << 3));                         \
    DST[mi][1] = *(const bf16x8*)(ap + (((4 | l4) ^ s8) << 3));                   \
  }

#define LDB(DST, NQ, BUFE)                                                        \
  _Pragma("unroll") for (int nj = 0; nj < 2; ++nj) {                              \
    int pr = wn * 32 + nj * 16 + l15;                                             \
    const unsigned short* bp = lB + (BUFE) + (NQ)*8192 + pr * 64;                 \
    int s8 = pr & 7;                                                              \
    DST[nj][0] = *(const bf16x8*)(bp + ((l4 ^ s8) << 3));                         \
    DST[nj][1] = *(const bf16x8*)(bp + (((4 | l4) ^ s8) << 3));                   \
  }

#define MFMAQ(MQ, NQ, AF, BF)                                                     \
  _Pragma("unroll") for (int ks = 0; ks < 2; ++ks)                                \
  _Pragma("unroll") for (int mi = 0; mi < 4; ++mi)                                \
  _Pragma("unroll") for (int nj = 0; nj < 2; ++nj)                                \
    acc[(MQ)*4 + mi][(NQ)*2 + nj] = __builtin_amdgcn_mfma_f32_16x16x32_bf16(      \
        AF[mi][ks], BF[nj][ks], acc[(MQ)*4 + mi][(NQ)*2 + nj], 0, 0, 0);

  f32x4 acc[8][4] = {};
  bf16x8 a0_[4][2], a1_[4][2], b0_[2][2], b1_[2][2];

  // ---- prologue: tile0 all 4 units + tile1 {A0,B0,B1}; wait tile0 (oldest 8 loads) ----
  STAGE_A(0, 0, 0) STAGE_B(0, 0, 0) STAGE_B(1, 0, 0) STAGE_A(1, 0, 0)
  STAGE_A(0, 1, 1) STAGE_B(0, 1, 1) STAGE_B(1, 1, 1)
  asm volatile("s_waitcnt vmcnt(6)" ::: "memory");
  __builtin_amdgcn_sched_barrier(0);
  __builtin_amdgcn_s_barrier();

  for (int t = 0; t < nt; ++t) {
    const int cbi = t & 1, nbi = cbi ^ 1;
    const int cb = cbi << 14;

    // ---- PH1: reads Aq0,Bq0 (12); stage A1(t+1)->nb; MFMA Q(0,0) ----
    LDA(a0_, 0, cb)
    LDB(b0_, 0, cb)
    STAGE_A(1, t + 1, nbi)
    asm volatile("s_waitcnt lgkmcnt(8)" ::: "memory");
    __builtin_amdgcn_sched_barrier(0);
    __builtin_amdgcn_s_barrier();
    asm volatile("s_waitcnt lgkmcnt(0)" ::: "memory");
    __builtin_amdgcn_sched_barrier(0);
    __builtin_amdgcn_s_setprio(1);
    MFMAQ(0, 0, a0_, b0_)
    __builtin_amdgcn_s_setprio(0);
    __builtin_amdgcn_s_barrier();

    // ---- PH2: reads Bq1 (4); stage A0(t+2)->cb; MFMA Q(0,1) ----
    LDB(b1_, 1, cb)
    STAGE_A(0, t + 2, cbi)
    __builtin_amdgcn_sched_barrier(0);
    __builtin_amdgcn_s_barrier();
    asm volatile("s_waitcnt lgkmcnt(0)" ::: "memory");
    __builtin_amdgcn_sched_barrier(0);
    __builtin_amdgcn_s_setprio(1);
    MFMAQ(0, 1, a0_, b1_)
    __builtin_amdgcn_s_setprio(0);
    __builtin_amdgcn_s_barrier();

    // ---- PH3: reads Aq1 (8); stage B0(t+2)->cb; MFMA Q(1,1) ----
    LDA(a1_, 1, cb)
    STAGE_B(0, t + 2, cbi)
    __builtin_amdgcn_sched_barrier(0);
    __builtin_amdgcn_s_barrier();
    asm volatile("s_waitcnt lgkmcnt(0)" ::: "memory");
    __builtin_amdgcn_sched_barrier(0);
    __builtin_amdgcn_s_setprio(1);
    MFMAQ(1, 1, a1_, b1_)
    __builtin_amdgcn_s_setprio(0);
    __builtin_amdgcn_s_barrier();

    // ---- PH4: no reads; stage B1(t+2)->cb; vmcnt(6); MFMA Q(1,0) ----
    STAGE_B(1, t + 2, cbi)
    asm volatile("s_waitcnt vmcnt(6)" ::: "memory");
    __builtin_amdgcn_sched_barrier(0);
    __builtin_amdgcn_s_barrier();
    __builtin_amdgcn_s_setprio(1);
    MFMAQ(1, 0, a1_, b0_)
    __builtin_amdgcn_s_setprio(0);
    __builtin_amdgcn_s_barrier();
  }

  asm volatile("s_waitcnt vmcnt(0)" ::: "memory");

  // ---- epilogue ----
  float s = gptr[0] / sqrtf(ssptr[0]);
#pragma unroll
  for (int nq = 0; nq < 2; ++nq)
#pragma unroll
    for (int nj = 0; nj < 2; ++nj) {
      int gcol = bn * 256 + wn * 64 + nq * 32 + nj * 16 + l15;
      float bv = bias[gcol];
#pragma unroll
      for (int mq = 0; mq < 2; ++mq)
#pragma unroll
        for (int mi = 0; mi < 4; ++mi)
#pragma unroll
          for (int r = 0; r < 4; ++r) {
            int grow = bm * 256 + wm * 128 + mq * 64 + mi * 16 + l4 * 4 + r;
            float v = fmaxf(acc[mq * 4 + mi][nq * 2 + nj][r] * s + bv, 0.f);
            C[(size_t)grow * N + gcol] = f2bf(v);
          }
    }
#undef STAGE_A
#undef STAGE_B
#undef LDA
#undef LDB
#undef MFMAQ
}

// ---------------- bf16 GEMM (m97 structure) for the small GEMM ----------------
__global__ __launch_bounds__(256, 2) void k_gemm_bt(
    const unsigned short* __restrict__ A, const unsigned short* __restrict__ B,
    const float* __restrict__ bias, const float* __restrict__ gptr,
    const float* __restrict__ ssptr, unsigned short* __restrict__ C,
    int M, int N, int K, int nbn) {
  __shared__ __align__(16) unsigned short lA[128 * 64];
  __shared__ __align__(16) unsigned short lB[128 * 64];
  int tid = threadIdx.x;
  int wid = tid >> 6, lane = tid & 63;
  int l15 = lane & 15, l4 = lane >> 4;
  int w0 = wid >> 1, w1 = wid & 1;

  int nwg = gridDim.x;
  int wg = blockIdx.x;
  int cpx = nwg >> 3;
  wg = (wg & 7) * cpx + (wg >> 3);
  int bm = wg / nbn, bn = wg % nbn;

  const unsigned short* Ab = A + (size_t)bm * 128 * K;
  const unsigned short* Bb = B + (size_t)bn * 128 * K;

  f32x4 acc[4][4] = {};

  for (int k0 = 0; k0 < K; k0 += 64) {
    __syncthreads();
#pragma unroll
    for (int i = 0; i < 4; ++i) {
      int ebase = (i * 4 + wid) << 9;
      int eoff = ebase + lane * 8;
      int row = eoff >> 6, col = eoff & 63;
      __builtin_amdgcn_global_load_lds(
          (gas_u32*)(Ab + (size_t)row * K + k0 + col),
          (las_u32*)(lA + ebase), 16, 0, 0);
      __builtin_amdgcn_global_load_lds(
          (gas_u32*)(Bb + (size_t)row * K + k0 + col),
          (las_u32*)(lB + ebase), 16, 0, 0);
    }
    __syncthreads();
#pragma unroll
    for (int ks = 0; ks < 2; ++ks) {
      bf16x8 af[4], bfr[4];
#pragma unroll
      for (int mi = 0; mi < 4; ++mi)
        af[mi] = *(const bf16x8*)(lA + ((w0 * 64 + mi * 16 + l15) * 64 + ks * 32 + l4 * 8));
#pragma unroll
      for (int nj = 0; nj < 4; ++nj)
        bfr[nj] = *(const bf16x8*)(lB + ((w1 * 64 + nj * 16 + l15) * 64 + ks * 32 + l4 * 8));
#pragma unroll
      for (int mi = 0; mi < 4; ++mi)
#pragma unroll
        for (int nj = 0; nj < 4; ++nj)
          acc[mi][nj] =
              __builtin_amdgcn_mfma_f32_16x16x32_bf16(af[mi], bfr[nj], acc[mi][nj], 0, 0, 0);
    }
  }

  float s = gptr[0] / sqrtf(ssptr[0]);
#pragma unroll
  for (int mi = 0; mi < 4; ++mi)
#pragma unroll
    for (int nj = 0; nj < 4; ++nj) {
      int col = bn * 128 + w1 * 64 + nj * 16 + l15;
      float bv = bias[col];
#pragma unroll
      for (int r = 0; r < 4; ++r) {
        int row = bm * 128 + w0 * 64 + mi * 16 + l4 * 4 + r;
        float v = fmaxf(acc[mi][nj][r] * s + bv, 0.f);
        C[(size_t)row * N + col] = f2bf(v);
      }
    }
}

// -------- glimpse (h-paired): out[b,h,v,q] = sum_k hm[h,k]*v_[b,v,k]*q_[b,q,k] + hb[h]
__global__ __launch_bounds__(256, 2) void k_glimpse2(
    const unsigned short* __restrict__ Vh, const unsigned short* __restrict__ Qh,
    const float* __restrict__ hmat, const float* __restrict__ hbias,
    float* __restrict__ out) {
  __shared__ __align__(16) unsigned short lV[128 * 64];
  __shared__ __align__(16) unsigned short lQ[2][32 * 64];
  int tid = threadIdx.x;
  int wid = tid >> 6, lane = tid & 63;
  int l15 = lane & 15, l4 = lane >> 4;

  int id = blockIdx.x;
  int b = id & 63, h2 = id >> 6;  // heads h2, h2+4

  const unsigned short* Vb = Vh + (size_t)b * 128 * 3072;
  const unsigned short* Qb = Qh + (size_t)b * 32 * 3072;
  const float* hr0 = hmat + h2 * 3072;
  const float* hr1 = hmat + (h2 + 4) * 3072;

  f32x4 acc[2][2][2] = {};

  int eoff = tid * 8;
  int qr = eoff >> 6, qc = eoff & 63;

  for (int k0 = 0; k0 < 3072; k0 += 64) {
    __syncthreads();
#pragma unroll
    for (int i = 0; i < 4; ++i) {
      int ebase = (i * 4 + wid) << 9;
      int eo = ebase + lane * 8;
      int row = eo >> 6, col = eo & 63;
      __builtin_amdgcn_global_load_lds(
          (gas_u32*)(Vb + (size_t)row * 3072 + k0 + col),
          (las_u32*)(lV + ebase), 16, 0, 0);
    }
    {
      uint4 qv = *(const uint4*)(Qb + (size_t)qr * 3072 + k0 + qc);
      float e0 = bf2f((unsigned short)(qv.x & 0xffff)), e1 = bf2f((unsigned short)(qv.x >> 16));
      float e2 = bf2f((unsigned short)(qv.y & 0xffff)), e3 = bf2f((unsigned short)(qv.y >> 16));
      float e4 = bf2f((unsigned short)(qv.z & 0xffff)), e5 = bf2f((unsigned short)(qv.z >> 16));
      float e6 = bf2f((unsigned short)(qv.w & 0xffff)), e7 = bf2f((unsigned short)(qv.w >> 16));
      const float* hp0 = hr0 + k0 + qc;
      const float* hp1 = hr1 + k0 + qc;
      float4 p00 = ((const float4*)hp0)[0], p01 = ((const float4*)hp0)[1];
      float4 p10 = ((const float4*)hp1)[0], p11 = ((const float4*)hp1)[1];
      uint4 o0, o1;
      o0.x = f2bf(e0 * p00.x) | ((unsigned)f2bf(e1 * p00.y) << 16);
      o0.y = f2bf(e2 * p00.z) | ((unsigned)f2bf(e3 * p00.w) << 16);
      o0.z = f2bf(e4 * p01.x) | ((unsigned)f2bf(e5 * p01.y) << 16);
      o0.w = f2bf(e6 * p01.z) | ((unsigned)f2bf(e7 * p01.w) << 16);
      o1.x = f2bf(e0 * p10.x) | ((unsigned)f2bf(e1 * p10.y) << 16);
      o1.y = f2bf(e2 * p10.z) | ((unsigned)f2bf(e3 * p10.w) << 16);
      o1.z = f2bf(e4 * p11.x) | ((unsigned)f2bf(e5 * p11.y) << 16);
      o1.w = f2bf(e6 * p11.z) | ((unsigned)f2bf(e7 * p11.w) << 16);
      *(uint4*)(lQ[0] + eoff) = o0;
      *(uint4*)(lQ[1] + eoff) = o1;
    }
    __syncthreads();
#pragma unroll
    for (int ks = 0; ks < 2; ++ks) {
      bf16x8 af[2];
#pragma unroll
      for (int mi = 0; mi < 2; ++mi)
        af[mi] = *(const bf16x8*)(lV + ((wid * 32 + mi * 16 + l15) * 64 + ks * 32 + l4 * 8));
#pragma unroll
      for (int hh = 0; hh < 2; ++hh) {
        bf16x8 bf2v[2];
#pragma unroll
        for (int nj = 0; nj < 2; ++nj)
          bf2v[nj] = *(const bf16x8*)(lQ[hh] + ((nj * 16 + l15) * 64 + ks * 32 + l4 * 8));
#pragma unroll
        for (int mi = 0; mi < 2; ++mi)
#pragma unroll
          for (int nj = 0; nj < 2; ++nj)
            acc[hh][mi][nj] = __builtin_amdgcn_mfma_f32_16x16x32_bf16(
                af[mi], bf2v[nj], acc[hh][mi][nj], 0, 0, 0);
      }
    }
  }

#pragma unroll
  for (int hh = 0; hh < 2; ++hh) {
    int h = h2 + hh * 4;
    float hb = hbias[h];
    float* ob = out + (size_t)(b * 8 + h) * 128 * 32;
#pragma unroll
    for (int mi = 0; mi < 2; ++mi)
#pragma unroll
      for (int nj = 0; nj < 2; ++nj)
#pragma unroll
        for (int r = 0; r < 4; ++r) {
          int row = wid * 32 + mi * 16 + l4 * 4 + r;
          int col = nj * 16 + l15;
          ob[row * 32 + col] = acc[hh][mi][nj][r] + hb;
        }
  }
}

extern "C" void kernel_launch(void* const* d_in, const int* in_sizes, int n_in,
                              void* d_out, int out_size, void* d_ws, size_t ws_size,
                              hipStream_t stream) {
  const float* v = (const float*)d_in[0];
  const float* q = (const float*)d_in[1];
  const float* v_w = (const float*)d_in[2];
  const float* v_g = (const float*)d_in[3];
  const float* v_b = (const float*)d_in[4];
  const float* q_w = (const float*)d_in[5];
  const float* q_g = (const float*)d_in[6];
  const float* q_b = (const float*)d_in[7];
  const float* hmat = (const float*)d_in[8];
  const float* hbias = (const float*)d_in[9];
  float* out = (float*)d_out;

  const size_t n_v = 16777216;   // 64*128*2048
  const size_t n_vw = 6291456;   // 3072*2048
  const size_t n_q = 2097152;    // 64*32*1024
  const size_t n_qw = 3145728;   // 3072*1024
  const size_t n_vh = 25165824;  // 8192*3072
  const size_t n_qh = 6291456;   // 2048*3072

  char* ws = (char*)d_ws;
  float* ss = (float*)ws;
  size_t off = 256;
  unsigned short* v_bf = (unsigned short*)(ws + off);  off += n_v * 2;
  unsigned short* vw_bf = (unsigned short*)(ws + off); off += n_vw * 2;
  unsigned short* q_bf = (unsigned short*)(ws + off);  off += n_q * 2;
  unsigned short* qw_bf = (unsigned short*)(ws + off); off += n_qw * 2;
  unsigned short* v_h = (unsigned short*)(ws + off);   off += n_vh * 2;
  unsigned short* q_h = (unsigned short*)(ws + off);   off += n_qh * 2;

  (void)hipMemsetAsync(ss, 0, 8, stream);
  k_sumsq<<<512, 256, 0, stream>>>(v_w, (int)(n_vw / 4), ss + 0);
  k_sumsq<<<512, 256, 0, stream>>>(q_w, (int)(n_qw / 4), ss + 1);

  k_cvt<<<1024, 256, 0, stream>>>(v, v_bf, (int)(n_v / 8));
  k_cvt<<<1024, 256, 0, stream>>>(v_w, vw_bf, (int)(n_vw / 8));
  k_cvt<<<1024, 256, 0, stream>>>(q, q_bf, (int)(n_q / 8));
  k_cvt<<<1024, 256, 0, stream>>>(q_w, qw_bf, (int)(n_qw / 8));

  // GEMM1: 8192x3072x2048, 256^2 tiles -> 32x12 = 384 blocks (%8==0)
  k_gemm8p<<<384, 512, 0, stream>>>(v_bf, vw_bf, v_b, v_g, ss + 0, v_h,
                                    8192, 3072, 2048, 12);
  // GEMM2: 2048x3072x1024, 128^2 tiles -> 16x24 = 384 blocks
  k_gemm_bt<<<384, 256, 0, stream>>>(q_bf, qw_bf, q_b, q_g, ss + 1, q_h,
                                     2048, 3072, 1024, 24);

  k_glimpse2<<<256, 256, 0, stream>>>(v_h, q_h, hmat, hbias, out);
}

// Round 5
// 236.366 us; speedup vs baseline: 1.2037x; 1.2037x over previous
//
#include <hip/hip_runtime.h>

typedef __attribute__((ext_vector_type(8))) __bf16 bf16x8;
typedef __attribute__((ext_vector_type(4))) float f32x4;
typedef const __attribute__((address_space(1))) unsigned int gas_u32;
typedef __attribute__((address_space(3))) unsigned int las_u32;

__device__ __forceinline__ unsigned short f2bf(float f) {
  unsigned u = __builtin_bit_cast(unsigned, f);
  u = (u + 0x7FFFu + ((u >> 16) & 1u)) >> 16;
  return (unsigned short)u;
}
__device__ __forceinline__ float bf2f(unsigned short h) {
  return __builtin_bit_cast(float, (unsigned)h << 16);
}

// ---------------- f32 -> bf16 convert (plain, for activations) ----------------
__global__ __launch_bounds__(256) void k_cvt(const float* __restrict__ in,
                                             unsigned short* __restrict__ out, int n8) {
  for (int i = blockIdx.x * 256 + threadIdx.x; i < n8; i += gridDim.x * 256) {
    float4 a = ((const float4*)in)[2 * i];
    float4 b = ((const float4*)in)[2 * i + 1];
    uint4 o;
    o.x = f2bf(a.x) | ((unsigned)f2bf(a.y) << 16);
    o.y = f2bf(a.z) | ((unsigned)f2bf(a.w) << 16);
    o.z = f2bf(b.x) | ((unsigned)f2bf(b.y) << 16);
    o.w = f2bf(b.z) | ((unsigned)f2bf(b.w) << 16);
    ((uint4*)out)[i] = o;
  }
}

// ------------- f32 -> bf16 convert + sum-of-squares (weights; reads w ONCE) -------------
__global__ __launch_bounds__(256) void k_cvt_sq(const float* __restrict__ in,
                                                unsigned short* __restrict__ out, int n8,
                                                float* __restrict__ ssout) {
  int tid = threadIdx.x;
  float s = 0.f;
  for (int i = blockIdx.x * 256 + tid; i < n8; i += gridDim.x * 256) {
    float4 a = ((const float4*)in)[2 * i];
    float4 b = ((const float4*)in)[2 * i + 1];
    s += a.x * a.x + a.y * a.y + a.z * a.z + a.w * a.w;
    s += b.x * b.x + b.y * b.y + b.z * b.z + b.w * b.w;
    uint4 o;
    o.x = f2bf(a.x) | ((unsigned)f2bf(a.y) << 16);
    o.y = f2bf(a.z) | ((unsigned)f2bf(a.w) << 16);
    o.z = f2bf(b.x) | ((unsigned)f2bf(b.y) << 16);
    o.w = f2bf(b.z) | ((unsigned)f2bf(b.w) << 16);
    ((uint4*)out)[i] = o;
  }
  for (int off = 32; off; off >>= 1) s += __shfl_down(s, off);
  __shared__ float red[4];
  if ((tid & 63) == 0) red[tid >> 6] = s;
  __syncthreads();
  if (tid == 0) atomicAdd(ssout, red[0] + red[1] + red[2] + red[3]);
}

// ======== GEMM1: 128x384 tile, 8 waves, read-ahead rotation, counted vmcnt ========
// bn-MAJOR decomposition: bn = wg/nbm, bm = wg%nbm. With the XCD swizzle each XCD
// owns ONE contiguous bn panel (384 cols x K x 2B = 1.6MB, L2-resident all kernel)
// and streams A once -> B re-reads come from L2 (34.5 TB/s) instead of LLC (~6.5).
// Stage units: u0,u1=A (8KB each); u2..u7=B. Per tile: ph0 stages u45(t+1)->np,
// ph2 stages u01(t+2)->cp, ph3 stages u23(t+2)+u67(t+2)->cp. Flights: u01 4ph,
// u23/u67 4ph, u45 3ph (round-3's u67 2-phase straggler fixed).
// Waits: ph2 vmcnt(6) [drains u01(t+1)]; ph3 vmcnt(2) [drains all B(t+1)].
__global__ __launch_bounds__(512, 2) void k_gemm_wn(
    const unsigned short* __restrict__ A, const unsigned short* __restrict__ B,
    const float* __restrict__ bias, const float* __restrict__ gptr,
    const float* __restrict__ ssptr, unsigned short* __restrict__ C,
    int M, int N, int K, int nbm) {
  __shared__ __align__(16) unsigned short lA[2 * 128 * 64];
  __shared__ __align__(16) unsigned short lB[2 * 384 * 64];
  const int tid = threadIdx.x;
  const int wid = tid >> 6, lane = tid & 63;
  const int l15 = lane & 15, l4 = lane >> 4;
  const int wm = wid >> 2, wn = wid & 3;  // 2M x 4N waves
  const int rr = tid >> 3;
  const int scol = ((tid & 7) ^ (rr & 7)) << 3;  // pre-swizzled source col (rule 21)

  // bijective XCD swizzle (gridDim.x % 8 == 0), then bn-major
  int nwg = gridDim.x;
  int wg = (blockIdx.x & 7) * (nwg >> 3) + (blockIdx.x >> 3);
  int bm = wg % nbm, bn = wg / nbm;

  const unsigned short* Ab = A + (size_t)bm * 128 * K;
  const unsigned short* Bb = B + (size_t)bn * 384 * K;
  const int nt = K >> 6;

#define STAGEU(U, TS)                                                            \
  {                                                                              \
    int ts_ = (TS) < nt ? (TS) : nt - 1;                                         \
    if ((U) < 2) {                                                               \
      __builtin_amdgcn_global_load_lds(                                          \
          (gas_u32*)(Ab + (size_t)((U)*64 + rr) * K + ts_ * 64 + scol),          \
          (las_u32*)(lA + ((TS)&1) * 8192 + (U)*4096 + tid * 8), 16, 0, 0);      \
    } else {                                                                     \
      __builtin_amdgcn_global_load_lds(                                          \
          (gas_u32*)(Bb + (size_t)(((U)-2) * 64 + rr) * K + ts_ * 64 + scol),    \
          (las_u32*)(lB + ((TS)&1) * 24576 + ((U)-2) * 4096 + tid * 8), 16, 0,   \
          0);                                                                    \
    }                                                                            \
  }

#define LDSA(DST, MQ, TP)                                                        \
  _Pragma("unroll") for (int i2 = 0; i2 < 2; ++i2) {                             \
    int rl = wm * 64 + ((MQ)*2 + i2) * 16 + l15;                                 \
    const unsigned short* ap = lA + (TP)*8192 + rl * 64;                         \
    int s8 = rl & 7;                                                             \
    DST[i2][0] = *(const bf16x8*)(ap + ((l4 ^ s8) << 3));                        \
    DST[i2][1] = *(const bf16x8*)(ap + (((4 | l4) ^ s8) << 3));                  \
  }

#define LDSB(DST, NQ, TP)                                                        \
  _Pragma("unroll") for (int j3 = 0; j3 < 3; ++j3) {                             \
    int rl = wn * 96 + ((NQ)*3 + j3) * 16 + l15;                                 \
    const unsigned short* bp = lB + (TP)*24576 + rl * 64;                        \
    int s8 = rl & 7;                                                             \
    DST[j3][0] = *(const bf16x8*)(bp + ((l4 ^ s8) << 3));                        \
    DST[j3][1] = *(const bf16x8*)(bp + (((4 | l4) ^ s8) << 3));                  \
  }

#define MFMA12(MQ, NQ, AF, BF)                                                   \
  _Pragma("unroll") for (int ks = 0; ks < 2; ++ks)                               \
  _Pragma("unroll") for (int i2 = 0; i2 < 2; ++i2)                               \
  _Pragma("unroll") for (int j3 = 0; j3 < 3; ++j3)                               \
    acc[(MQ)*2 + i2][(NQ)*3 + j3] = __builtin_amdgcn_mfma_f32_16x16x32_bf16(     \
        AF[i2][ks], BF[j3][ks], acc[(MQ)*2 + i2][(NQ)*3 + j3], 0, 0, 0);

  f32x4 acc[4][6] = {};
  bf16x8 a0_[2][2], a1_[2][2], b0_[3][2], b1_[3][2];

  // ---- prologue: tile0 u0-7 + u01(1); wait tile0; then u23(1), u67(1) ----
  STAGEU(0, 0) STAGEU(1, 0) STAGEU(2, 0) STAGEU(3, 0)
  STAGEU(4, 0) STAGEU(5, 0) STAGEU(6, 0) STAGEU(7, 0)
  STAGEU(0, 1) STAGEU(1, 1)
  asm volatile("s_waitcnt vmcnt(2)" ::: "memory");
  __builtin_amdgcn_sched_barrier(0);
  __builtin_amdgcn_s_barrier();
  LDSA(a0_, 0, 0)
  STAGEU(2, 1) STAGEU(3, 1) STAGEU(6, 1) STAGEU(7, 1)
  LDSB(b0_, 0, 0)

  for (int t = 0; t < nt; ++t) {
    const int cp = t & 1, np = (t + 1) & 1;
    // ---- ph0: read b1_(t); stage u45(t+1)->np; MFMA q00 ----
    LDSB(b1_, 1, cp)
    STAGEU(4, t + 1) STAGEU(5, t + 1)
    __builtin_amdgcn_s_setprio(1);
    MFMA12(0, 0, a0_, b0_)
    __builtin_amdgcn_s_setprio(0);
    // ---- ph1: read a1_(t); MFMA q01 ----
    LDSA(a1_, 1, cp)
    __builtin_amdgcn_s_setprio(1);
    MFMA12(0, 1, a0_, b1_)
    __builtin_amdgcn_s_setprio(0);
    // ---- ph2: lgkm0 (WAR: buf reads done) + vmcnt(6) (u01(t+1) landed) + barrier;
    //          read a0_(t+1); stage u01(t+2)->cp; MFMA q10 ----
    asm volatile("s_waitcnt lgkmcnt(0)" ::: "memory");
    asm volatile("s_waitcnt vmcnt(6)" ::: "memory");
    __builtin_amdgcn_sched_barrier(0);
    __builtin_amdgcn_s_barrier();
    LDSA(a0_, 0, np)
    STAGEU(0, t + 2) STAGEU(1, t + 2)
    __builtin_amdgcn_s_setprio(1);
    MFMA12(1, 0, a1_, b0_)
    __builtin_amdgcn_s_setprio(0);
    // ---- ph3: vmcnt(2) (all B(t+1) landed) + barrier; read b0_(t+1);
    //          stage u23(t+2)+u67(t+2)->cp; MFMA q11 ----
    asm volatile("s_waitcnt vmcnt(2)" ::: "memory");
    __builtin_amdgcn_sched_barrier(0);
    __builtin_amdgcn_s_barrier();
    LDSB(b0_, 0, np)
    STAGEU(2, t + 2) STAGEU(3, t + 2) STAGEU(6, t + 2) STAGEU(7, t + 2)
    __builtin_amdgcn_s_setprio(1);
    MFMA12(1, 1, a1_, b1_)
    __builtin_amdgcn_s_setprio(0);
  }

  asm volatile("s_waitcnt vmcnt(0)" ::: "memory");

  float s = gptr[0] / sqrtf(ssptr[0]);
#pragma unroll
  for (int nj = 0; nj < 6; ++nj) {
    int gcol = bn * 384 + wn * 96 + nj * 16 + l15;
    float bv = bias[gcol];
#pragma unroll
    for (int mi = 0; mi < 4; ++mi) {
#pragma unroll
      for (int r = 0; r < 4; ++r) {
        int grow = bm * 128 + wm * 64 + mi * 16 + l4 * 4 + r;
        float v = fmaxf(acc[mi][nj][r] * s + bv, 0.f);
        C[(size_t)grow * N + gcol] = f2bf(v);
      }
    }
  }
#undef STAGEU
#undef LDSA
#undef LDSB
#undef MFMA12
}

// ---------------- bf16 GEMM (m97 structure) for the small GEMM; bn-major ----------------
__global__ __launch_bounds__(256, 2) void k_gemm_bt(
    const unsigned short* __restrict__ A, const unsigned short* __restrict__ B,
    const float* __restrict__ bias, const float* __restrict__ gptr,
    const float* __restrict__ ssptr, unsigned short* __restrict__ C,
    int M, int N, int K, int nbm) {
  __shared__ __align__(16) unsigned short lA[128 * 64];
  __shared__ __align__(16) unsigned short lB[128 * 64];
  int tid = threadIdx.x;
  int wid = tid >> 6, lane = tid & 63;
  int l15 = lane & 15, l4 = lane >> 4;
  int w0 = wid >> 1, w1 = wid & 1;

  int nwg = gridDim.x;
  int wg = (blockIdx.x & 7) * (nwg >> 3) + (blockIdx.x >> 3);
  int bm = wg % nbm, bn = wg / nbm;

  const unsigned short* Ab = A + (size_t)bm * 128 * K;
  const unsigned short* Bb = B + (size_t)bn * 128 * K;

  f32x4 acc[4][4] = {};

  for (int k0 = 0; k0 < K; k0 += 64) {
    __syncthreads();
#pragma unroll
    for (int i = 0; i < 4; ++i) {
      int ebase = (i * 4 + wid) << 9;
      int eoff = ebase + lane * 8;
      int row = eoff >> 6, col = eoff & 63;
      __builtin_amdgcn_global_load_lds(
          (gas_u32*)(Ab + (size_t)row * K + k0 + col),
          (las_u32*)(lA + ebase), 16, 0, 0);
      __builtin_amdgcn_global_load_lds(
          (gas_u32*)(Bb + (size_t)row * K + k0 + col),
          (las_u32*)(lB + ebase), 16, 0, 0);
    }
    __syncthreads();
#pragma unroll
    for (int ks = 0; ks < 2; ++ks) {
      bf16x8 af[4], bfr[4];
#pragma unroll
      for (int mi = 0; mi < 4; ++mi)
        af[mi] = *(const bf16x8*)(lA + ((w0 * 64 + mi * 16 + l15) * 64 + ks * 32 + l4 * 8));
#pragma unroll
      for (int nj = 0; nj < 4; ++nj)
        bfr[nj] = *(const bf16x8*)(lB + ((w1 * 64 + nj * 16 + l15) * 64 + ks * 32 + l4 * 8));
#pragma unroll
      for (int mi = 0; mi < 4; ++mi)
#pragma unroll
        for (int nj = 0; nj < 4; ++nj)
          acc[mi][nj] =
              __builtin_amdgcn_mfma_f32_16x16x32_bf16(af[mi], bfr[nj], acc[mi][nj], 0, 0, 0);
    }
  }

  float s = gptr[0] / sqrtf(ssptr[0]);
#pragma unroll
  for (int mi = 0; mi < 4; ++mi)
#pragma unroll
    for (int nj = 0; nj < 4; ++nj) {
      int col = bn * 128 + w1 * 64 + nj * 16 + l15;
      float bv = bias[col];
#pragma unroll
      for (int r = 0; r < 4; ++r) {
        int row = bm * 128 + w0 * 64 + mi * 16 + l4 * 4 + r;
        float v = fmaxf(acc[mi][nj][r] * s + bv, 0.f);
        C[(size_t)row * N + col] = f2bf(v);
      }
    }
}

// -------- glimpse v3: pipelined. out[b,h,v,q] = sum_k hm[h,k]*v_[b,v,k]*q_[b,q,k] + hb[h]
// block = (h2*64 + b): same-b blocks share an XCD (V/Q L2-shared). Triple-buffered V
// (depth-2 flight), double-buffered lQ + Q-regs (unroll-2). Per iter: 1 barrier,
// vmcnt(9) (keeps V(t+1)[4] + Qld(t+2)[5] in flight), lgkm0 publishes ds_writes.
// Counter sim: iter t outstanding before wait = V(t)4,Qld(t+1)5,V(t+1)4,Qld(t+2)5=18;
// vmcnt(9) drains V(t)+Qld(t+1) (both consumed this iter), keeps 9.
__global__ __launch_bounds__(256, 2) void k_glimpse3(
    const unsigned short* __restrict__ Vh, const unsigned short* __restrict__ Qh,
    const float* __restrict__ hmat, const float* __restrict__ hbias,
    float* __restrict__ out) {
  __shared__ __align__(16) unsigned short lV[3][128 * 64];
  __shared__ __align__(16) unsigned short lQ[2][2][32 * 64];
  int tid = threadIdx.x;
  int wid = tid >> 6, lane = tid & 63;
  int l15 = lane & 15, l4 = lane >> 4;

  int id = blockIdx.x;
  int b = id & 63, h2 = id >> 6;  // heads h2, h2+4

  const unsigned short* Vb = Vh + (size_t)b * 128 * 3072;
  const unsigned short* Qb = Qh + (size_t)b * 32 * 3072;
  const float* hr0 = hmat + h2 * 3072;
  const float* hr1 = hmat + (h2 + 4) * 3072;

  f32x4 acc[2][2][2] = {};
  int eoff = tid * 8;
  int qr = eoff >> 6, qc = eoff & 63;
  const int NT = 48;

#define VSTAGE(T, SLOT)                                                          \
  {                                                                              \
    int tc = (T) < NT ? (T) : NT - 1;                                            \
    _Pragma("unroll") for (int i = 0; i < 4; ++i) {                              \
      int ebase = (i * 4 + wid) << 9;                                            \
      int eo = ebase + lane * 8;                                                 \
      int row = eo >> 6, col = eo & 63;                                          \
      __builtin_amdgcn_global_load_lds(                                          \
          (gas_u32*)(Vb + (size_t)row * 3072 + tc * 64 + col),                   \
          (las_u32*)(&lV[SLOT][0] + ebase), 16, 0, 0);                           \
    }                                                                            \
  }

#define QLOAD(T, RQ, H0A, H0B, H1A, H1B)                                         \
  {                                                                              \
    int tc = (T) < NT ? (T) : NT - 1;                                            \
    RQ = *(const uint4*)(Qb + (size_t)qr * 3072 + tc * 64 + qc);                 \
    const float* hp0 = hr0 + tc * 64 + qc;                                       \
    const float* hp1 = hr1 + tc * 64 + qc;                                       \
    H0A = ((const float4*)hp0)[0];                                               \
    H0B = ((const float4*)hp0)[1];                                               \
    H1A = ((const float4*)hp1)[0];                                               \
    H1B = ((const float4*)hp1)[1];                                               \
  }

#define QWRITE(CB, RQ, H0A, H0B, H1A, H1B)                                       \
  {                                                                              \
    float e0 = bf2f((unsigned short)(RQ.x & 0xffff));                            \
    float e1 = bf2f((unsigned short)(RQ.x >> 16));                               \
    float e2 = bf2f((unsigned short)(RQ.y & 0xffff));                            \
    float e3 = bf2f((unsigned short)(RQ.y >> 16));                               \
    float e4 = bf2f((unsigned short)(RQ.z & 0xffff));                            \
    float e5 = bf2f((unsigned short)(RQ.z >> 16));                               \
    float e6 = bf2f((unsigned short)(RQ.w & 0xffff));                            \
    float e7 = bf2f((unsigned short)(RQ.w >> 16));                               \
    uint4 o0, o1;                                                                \
    o0.x = f2bf(e0 * H0A.x) | ((unsigned)f2bf(e1 * H0A.y) << 16);                \
    o0.y = f2bf(e2 * H0A.z) | ((unsigned)f2bf(e3 * H0A.w) << 16);                \
    o0.z = f2bf(e4 * H0B.x) | ((unsigned)f2bf(e5 * H0B.y) << 16);                \
    o0.w = f2bf(e6 * H0B.z) | ((unsigned)f2bf(e7 * H0B.w) << 16);                \
    o1.x = f2bf(e0 * H1A.x) | ((unsigned)f2bf(e1 * H1A.y) << 16);                \
    o1.y = f2bf(e2 * H1A.z) | ((unsigned)f2bf(e3 * H1A.w) << 16);                \
    o1.z = f2bf(e4 * H1B.x) | ((unsigned)f2bf(e5 * H1B.y) << 16);                \
    o1.w = f2bf(e6 * H1B.z) | ((unsigned)f2bf(e7 * H1B.w) << 16);                \
    *(uint4*)(&lQ[CB][0][0] + eoff) = o0;                                        \
    *(uint4*)(&lQ[CB][1][0] + eoff) = o1;                                        \
  }

#define GMFMA(SLOT, CB)                                                          \
  _Pragma("unroll") for (int ks = 0; ks < 2; ++ks) {                             \
    bf16x8 af[2];                                                                \
    _Pragma("unroll") for (int mi = 0; mi < 2; ++mi)                             \
      af[mi] = *(const bf16x8*)(&lV[SLOT][0] +                                   \
                                ((wid * 32 + mi * 16 + l15) * 64 + ks * 32 + l4 * 8)); \
    _Pragma("unroll") for (int hh = 0; hh < 2; ++hh) {                           \
      bf16x8 bq[2];                                                              \
      _Pragma("unroll") for (int nj = 0; nj < 2; ++nj)                           \
        bq[nj] = *(const bf16x8*)(&lQ[CB][hh][0] +                               \
                                  ((nj * 16 + l15) * 64 + ks * 32 + l4 * 8));    \
      _Pragma("unroll") for (int mi = 0; mi < 2; ++mi)                           \
        _Pragma("unroll") for (int nj = 0; nj < 2; ++nj)                         \
          acc[hh][mi][nj] = __builtin_amdgcn_mfma_f32_16x16x32_bf16(             \
              af[mi], bq[nj], acc[hh][mi][nj], 0, 0, 0);                         \
    }                                                                            \
  }

  // GBODY(T, C*, N*): consume Q(T+1) from C-set, load Q(T+2) into N-set.
#define GBODY(T, CQ, CH0A, CH0B, CH1A, CH1B, NQ, NH0A, NH0B, NH1A, NH1B)         \
  {                                                                              \
    QLOAD((T) + 2, NQ, NH0A, NH0B, NH1A, NH1B)                                   \
    asm volatile("s_waitcnt vmcnt(9)" ::: "memory");                             \
    asm volatile("s_waitcnt lgkmcnt(0)" ::: "memory");                           \
    __builtin_amdgcn_sched_barrier(0);                                           \
    __builtin_amdgcn_s_barrier();                                                \
    VSTAGE((T) + 2, ((T) + 2) % 3)                                               \
    QWRITE(((T) + 1) & 1, CQ, CH0A, CH0B, CH1A, CH1B)                            \
    GMFMA((T) % 3, (T) & 1)                                                      \
  }

  uint4 aq, bq_;
  float4 ah0a, ah0b, ah1a, ah1b, bh0a, bh0b, bh1a, bh1b;

  // ---- prologue: Qld(0)->A, Qld(1)->B, V(0), V(1); wait Qld(0); write lQ[0] ----
  QLOAD(0, aq, ah0a, ah0b, ah1a, ah1b)
  QLOAD(1, bq_, bh0a, bh0b, bh1a, bh1b)
  VSTAGE(0, 0)
  VSTAGE(1, 1)
  asm volatile("s_waitcnt vmcnt(13)" ::: "memory");
  __builtin_amdgcn_sched_barrier(0);
  QWRITE(0, aq, ah0a, ah0b, ah1a, ah1b)

  for (int t = 0; t < NT; t += 2) {
    GBODY(t, bq_, bh0a, bh0b, bh1a, bh1b, aq, ah0a, ah0b, ah1a, ah1b)
    GBODY(t + 1, aq, ah0a, ah0b, ah1a, ah1b, bq_, bh0a, bh0b, bh1a, bh1b)
  }
  asm volatile("s_waitcnt vmcnt(0) lgkmcnt(0)" ::: "memory");

#pragma unroll
  for (int hh = 0; hh < 2; ++hh) {
    int h = h2 + hh * 4;
    float hb = hbias[h];
    float* ob = out + (size_t)(b * 8 + h) * 128 * 32;
#pragma unroll
    for (int mi = 0; mi < 2; ++mi)
#pragma unroll
      for (int nj = 0; nj < 2; ++nj)
#pragma unroll
        for (int r = 0; r < 4; ++r) {
          int row = wid * 32 + mi * 16 + l4 * 4 + r;
          int col = nj * 16 + l15;
          ob[row * 32 + col] = acc[hh][mi][nj][r] + hb;
        }
  }
#undef VSTAGE
#undef QLOAD
#undef QWRITE
#undef GMFMA
#undef GBODY
}

extern "C" void kernel_launch(void* const* d_in, const int* in_sizes, int n_in,
                              void* d_out, int out_size, void* d_ws, size_t ws_size,
                              hipStream_t stream) {
  const float* v = (const float*)d_in[0];
  const float* q = (const float*)d_in[1];
  const float* v_w = (const float*)d_in[2];
  const float* v_g = (const float*)d_in[3];
  const float* v_b = (const float*)d_in[4];
  const float* q_w = (const float*)d_in[5];
  const float* q_g = (const float*)d_in[6];
  const float* q_b = (const float*)d_in[7];
  const float* hmat = (const float*)d_in[8];
  const float* hbias = (const float*)d_in[9];
  float* out = (float*)d_out;

  const size_t n_v = 16777216;   // 64*128*2048
  const size_t n_vw = 6291456;   // 3072*2048
  const size_t n_q = 2097152;    // 64*32*1024
  const size_t n_qw = 3145728;   // 3072*1024
  const size_t n_vh = 25165824;  // 8192*3072
  const size_t n_qh = 6291456;   // 2048*3072

  char* ws = (char*)d_ws;
  float* ss = (float*)ws;
  size_t off = 256;
  unsigned short* v_bf = (unsigned short*)(ws + off);  off += n_v * 2;
  unsigned short* vw_bf = (unsigned short*)(ws + off); off += n_vw * 2;
  unsigned short* q_bf = (unsigned short*)(ws + off);  off += n_q * 2;
  unsigned short* qw_bf = (unsigned short*)(ws + off); off += n_qw * 2;
  unsigned short* v_h = (unsigned short*)(ws + off);   off += n_vh * 2;
  unsigned short* q_h = (unsigned short*)(ws + off);   off += n_qh * 2;

  (void)hipMemsetAsync(ss, 0, 8, stream);
  k_cvt_sq<<<512, 256, 0, stream>>>(v_w, vw_bf, (int)(n_vw / 8), ss + 0);
  k_cvt_sq<<<512, 256, 0, stream>>>(q_w, qw_bf, (int)(n_qw / 8), ss + 1);
  k_cvt<<<1024, 256, 0, stream>>>(v, v_bf, (int)(n_v / 8));
  k_cvt<<<1024, 256, 0, stream>>>(q, q_bf, (int)(n_q / 8));

  // GEMM1: 8192x3072x2048, 128x384 tiles -> 64 bm x 8 bn = 512 blocks (bn-major)
  k_gemm_wn<<<512, 512, 0, stream>>>(v_bf, vw_bf, v_b, v_g, ss + 0, v_h,
                                     8192, 3072, 2048, 64);
  // GEMM2: 2048x3072x1024, 128^2 tiles -> 16 bm x 24 bn = 384 blocks (bn-major)
  k_gemm_bt<<<384, 256, 0, stream>>>(q_bf, qw_bf, q_b, q_g, ss + 1, q_h,
                                     2048, 3072, 1024, 16);

  k_glimpse3<<<256, 256, 0, stream>>>(v_h, q_h, hmat, hbias, out);
}